// Round 1
// baseline (1741.143 us; speedup 1.0000x reference)
//
#include <hip/hip_runtime.h>
#include <math.h>

#define Bdim 8
#define Sdim 1024
#define Hdim 1024
#define NHd 16
#define HDd 64
#define N3H 3072                      // 3*H
#define QSZ (Bdim*NHd*Sdim*HDd)       // 8388608 elements per Q/K/V plane

// ---------------- QKV GEMM ----------------
// C(M=8192, N=3072) = A(8192,1024) * W(1024,3072) + bias, scattered to
// ws[which][b][h][s][d] with which=(col/64)%3, h=col/192, d=col%64.
#define BM 64
#define BN 64
#define BK 32

__global__ __launch_bounds__(256, 2) void qkv_gemm(
    const float* __restrict__ A, const float* __restrict__ W,
    const float* __restrict__ bias, float* __restrict__ ws)
{
  __shared__ float As[BK][BM + 4];   // [k][m], padded
  __shared__ float Bs[BK][BN + 4];   // [k][n], padded

  const int tid = threadIdx.x;
  const int tx = tid & 15, ty = tid >> 4;
  const int m0 = blockIdx.y * BM;
  const int n0 = blockIdx.x * BN;

  float acc[4][4] = {};

  for (int kt = 0; kt < Hdim; kt += BK) {
    // A tile: 64 rows x 32 cols -> As[k][m] (transposed store)
    #pragma unroll
    for (int r = 0; r < 2; ++r) {
      int t2 = tid + r * 256;
      int arow = t2 >> 3;       // 0..63
      int ac4  = t2 & 7;        // 0..7 (float4 index)
      float4 v = *(const float4*)&A[(size_t)(m0 + arow) * Hdim + kt + ac4 * 4];
      As[ac4 * 4 + 0][arow] = v.x;
      As[ac4 * 4 + 1][arow] = v.y;
      As[ac4 * 4 + 2][arow] = v.z;
      As[ac4 * 4 + 3][arow] = v.w;
    }
    // B tile: 32 rows x 64 cols -> Bs[k][n]
    #pragma unroll
    for (int r = 0; r < 2; ++r) {
      int t2 = tid + r * 256;
      int brow = t2 >> 4;       // 0..31
      int bc4  = t2 & 15;       // 0..15
      *(float4*)&Bs[brow][bc4 * 4] =
          *(const float4*)&W[(size_t)(kt + brow) * N3H + n0 + bc4 * 4];
    }
    __syncthreads();

    #pragma unroll
    for (int kk = 0; kk < BK; ++kk) {
      float4 a4 = *(float4*)&As[kk][ty * 4];
      float4 b4 = *(float4*)&Bs[kk][tx * 4];
      float a[4] = {a4.x, a4.y, a4.z, a4.w};
      float b[4] = {b4.x, b4.y, b4.z, b4.w};
      #pragma unroll
      for (int i = 0; i < 4; ++i)
        #pragma unroll
        for (int j = 0; j < 4; ++j)
          acc[i][j] += a[i] * b[j];
    }
    __syncthreads();
  }

  // Epilogue: this block's 64 cols lie in exactly one (which, head) slice.
  const int which = (n0 / HDd) % 3;
  const int head  = n0 / (3 * HDd);
  const int bb    = m0 / Sdim;
  const int sbase = m0 % Sdim;
  float* dst = ws + (size_t)which * QSZ +
               ((size_t)(bb * NHd + head) * Sdim + sbase) * HDd;
  float4 bias4 = *(const float4*)&bias[n0 + tx * 4];
  #pragma unroll
  for (int i = 0; i < 4; ++i) {
    int lr = ty * 4 + i;
    float4 o;
    o.x = acc[i][0] + bias4.x;
    o.y = acc[i][1] + bias4.y;
    o.z = acc[i][2] + bias4.z;
    o.w = acc[i][3] + bias4.w;
    *(float4*)&dst[(size_t)lr * HDd + tx * 4] = o;
  }
}

// ---------------- Attention ----------------
// One thread = one query. Block = 256 queries of one (b,h).
// K/V staged in LDS 64 keys at a time; online softmax with 16-key chunks.
__global__ __launch_bounds__(256, 2) void attn(
    const float* __restrict__ ws, const int* __restrict__ mask,
    float* __restrict__ out)
{
  const float* Q = ws;
  const float* K = ws + (size_t)QSZ;
  const float* V = ws + 2 * (size_t)QSZ;

  __shared__ float4 Kt[64 * 16];   // [key][d4]
  __shared__ float4 Vt[64 * 16];
  __shared__ float  msk[64];       // 1.0 if masked (-> -10000), else 0.0

  const int tid = threadIdx.x;
  const int qt = blockIdx.x & 3;          // S/256 = 4 query tiles
  const int bh = blockIdx.x >> 2;         // b*NH + h
  const int bb = bh >> 4;                 // b
  const int sq = qt * 256 + tid;

  const float4* qrow = (const float4*)(Q + ((size_t)bh * Sdim + sq) * HDd);
  float4 q4[16];
  #pragma unroll
  for (int d = 0; d < 16; ++d) q4[d] = qrow[d];

  float4 acc4[16];
  #pragma unroll
  for (int d = 0; d < 16; ++d) acc4[d] = make_float4(0.f, 0.f, 0.f, 0.f);
  float m = -INFINITY, l = 0.f;

  for (int kt = 0; kt < Sdim / 64; ++kt) {
    __syncthreads();
    const float4* ksrc = (const float4*)(K + ((size_t)bh * Sdim + kt * 64) * HDd);
    const float4* vsrc = (const float4*)(V + ((size_t)bh * Sdim + kt * 64) * HDd);
    #pragma unroll
    for (int r = 0; r < 4; ++r) {
      Kt[tid + r * 256] = ksrc[tid + r * 256];
      Vt[tid + r * 256] = vsrc[tid + r * 256];
    }
    if (tid < 64)
      msk[tid] = (mask[bb * Sdim + kt * 64 + tid] != 0) ? 1.f : 0.f;
    __syncthreads();

    #pragma unroll 1
    for (int g = 0; g < 4; ++g) {
      float sc[16];
      float gm = -INFINITY;
      #pragma unroll
      for (int j = 0; j < 16; ++j) {
        int key = g * 16 + j;
        float4 s4 = make_float4(0.f, 0.f, 0.f, 0.f);
        #pragma unroll
        for (int d = 0; d < 16; ++d) {
          float4 k4 = Kt[key * 16 + d];
          s4.x += q4[d].x * k4.x;
          s4.y += q4[d].y * k4.y;
          s4.z += q4[d].z * k4.z;
          s4.w += q4[d].w * k4.w;
        }
        float s = (s4.x + s4.y) + (s4.z + s4.w);
        // reference: scores*8 then where(mask!=0, -10000, .)
        s = (msk[key] != 0.f) ? -10000.f : s * 8.f;
        sc[j] = s;
        gm = fmaxf(gm, s);
      }
      float mn = fmaxf(m, gm);
      float alpha = __expf(m - mn);       // exp(-inf)=0 first time
      l *= alpha;
      #pragma unroll
      for (int d = 0; d < 16; ++d) {
        acc4[d].x *= alpha; acc4[d].y *= alpha;
        acc4[d].z *= alpha; acc4[d].w *= alpha;
      }
      #pragma unroll
      for (int j = 0; j < 16; ++j) {
        int key = g * 16 + j;
        float p = __expf(sc[j] - mn);
        l += p;
        #pragma unroll
        for (int d = 0; d < 16; ++d) {
          float4 v4 = Vt[key * 16 + d];
          acc4[d].x += p * v4.x; acc4[d].y += p * v4.y;
          acc4[d].z += p * v4.z; acc4[d].w += p * v4.w;
        }
      }
      m = mn;
    }
  }

  const float inv = 1.f / l;
  float4* orow = (float4*)(out + ((size_t)bb * Sdim + sq) * Hdim + (bh & 15) * HDd);
  #pragma unroll
  for (int d = 0; d < 16; ++d) {
    float4 o = acc4[d];
    o.x *= inv; o.y *= inv; o.z *= inv; o.w *= inv;
    orow[d] = o;
  }
}

extern "C" void kernel_launch(void* const* d_in, const int* in_sizes, int n_in,
                              void* d_out, int out_size, void* d_ws, size_t ws_size,
                              hipStream_t stream) {
  const float* hs   = (const float*)d_in[0];
  const int*   mask = (const int*)d_in[1];
  const float* w    = (const float*)d_in[2];
  const float* bias = (const float*)d_in[3];
  float* out = (float*)d_out;
  float* ws  = (float*)d_ws;   // needs 3*QSZ*4 = 100.7 MB

  dim3 gg(N3H / BN, (Bdim * Sdim) / BM);   // (48, 128)
  qkv_gemm<<<gg, 256, 0, stream>>>(hs, w, bias, ws);
  attn<<<Bdim * NHd * (Sdim / 256), 256, 0, stream>>>(ws, mask, out);
}

// Round 3
// 895.108 us; speedup vs baseline: 1.9452x; 1.9452x over previous
//
#include <hip/hip_runtime.h>
#include <math.h>

#define Bdim 8
#define Sdim 1024
#define Hdim 1024
#define NHd 16
#define HDd 64
#define N3H 3072

// ws layout (ushort/bf16 elements): Qhl [bh][s][128], Khl [bh][s][128], Vt [bh][d][s]
#define Q_OFF  0u
#define K_OFF  16777216u
#define V_OFF  33554432u

typedef __bf16 bf16x8 __attribute__((ext_vector_type(8)));
typedef float  f32x4  __attribute__((ext_vector_type(4)));

__device__ __forceinline__ unsigned short f2bf(float x) {
  unsigned b = __builtin_bit_cast(unsigned, x);
  return (unsigned short)((b + 0x7FFFu + ((b >> 16) & 1u)) >> 16);
}

// ---------------- QKV GEMM (fp32 compute, bf16 hi/lo epilogue) ----------------
#define BM 64
#define BN 64
#define BK 32

__global__ __launch_bounds__(256, 2) void qkv_gemm(
    const float* __restrict__ A, const float* __restrict__ W,
    const float* __restrict__ bias, unsigned short* __restrict__ ws)
{
  __shared__ float smem[4352];                  // As[32][68] + Bs[32][68]; reused as Ts[64][65]
  float (*As)[BM + 4] = (float(*)[BM + 4])smem;
  float (*Bs)[BN + 4] = (float(*)[BN + 4])(smem + 32 * (BM + 4));

  const int tid = threadIdx.x;
  const int tx = tid & 15, ty = tid >> 4;
  const int m0 = blockIdx.y * BM;
  const int n0 = blockIdx.x * BN;

  float acc[4][4] = {};

  for (int kt = 0; kt < Hdim; kt += BK) {
    #pragma unroll
    for (int r = 0; r < 2; ++r) {
      int t2 = tid + r * 256;
      int arow = t2 >> 3;
      int ac4  = t2 & 7;
      float4 v = *(const float4*)&A[(size_t)(m0 + arow) * Hdim + kt + ac4 * 4];
      As[ac4 * 4 + 0][arow] = v.x;
      As[ac4 * 4 + 1][arow] = v.y;
      As[ac4 * 4 + 2][arow] = v.z;
      As[ac4 * 4 + 3][arow] = v.w;
    }
    #pragma unroll
    for (int r = 0; r < 2; ++r) {
      int t2 = tid + r * 256;
      int brow = t2 >> 4;
      int bc4  = t2 & 15;
      *(float4*)&Bs[brow][bc4 * 4] =
          *(const float4*)&W[(size_t)(kt + brow) * N3H + n0 + bc4 * 4];
    }
    __syncthreads();

    #pragma unroll
    for (int kk = 0; kk < BK; ++kk) {
      float4 a4 = *(float4*)&As[kk][ty * 4];
      float4 b4 = *(float4*)&Bs[kk][tx * 4];
      float a[4] = {a4.x, a4.y, a4.z, a4.w};
      float b[4] = {b4.x, b4.y, b4.z, b4.w};
      #pragma unroll
      for (int i = 0; i < 4; ++i)
        #pragma unroll
        for (int j = 0; j < 4; ++j)
          acc[i][j] += a[i] * b[j];
    }
    __syncthreads();
  }

  const int which = (n0 / HDd) % 3;
  const int head  = n0 / (3 * HDd);
  const int bb    = m0 / Sdim;
  const int sbase = m0 % Sdim;

  float4 bias4 = *(const float4*)&bias[n0 + tx * 4];
  float ov[4][4];
  #pragma unroll
  for (int i = 0; i < 4; ++i) {
    ov[i][0] = acc[i][0] + bias4.x;
    ov[i][1] = acc[i][1] + bias4.y;
    ov[i][2] = acc[i][2] + bias4.z;
    ov[i][3] = acc[i][3] + bias4.w;
  }

  if (which < 2) {
    // Q/K: write hi at d, lo at 64+d in [bh][s][128] plane
    unsigned short* dst = ws + (which == 0 ? Q_OFF : K_OFF) +
        ((size_t)(bb * NHd + head) * Sdim + sbase) * 128;
    #pragma unroll
    for (int i = 0; i < 4; ++i) {
      int lr = ty * 4 + i;
      unsigned short hi[4], lo[4];
      #pragma unroll
      for (int j = 0; j < 4; ++j) {
        float o = ov[i][j];
        unsigned short h = f2bf(o);
        unsigned hb = ((unsigned)h) << 16;
        float res = o - __builtin_bit_cast(float, hb);
        hi[j] = h;
        lo[j] = f2bf(res);
      }
      *(uint2*)&dst[(size_t)lr * 128 + tx * 4]      = *(uint2*)hi;
      *(uint2*)&dst[(size_t)lr * 128 + 64 + tx * 4] = *(uint2*)lo;
    }
  } else {
    // V: transpose through LDS, write bf16 [bh][d][s]
    #pragma unroll
    for (int i = 0; i < 4; ++i)
      #pragma unroll
      for (int j = 0; j < 4; ++j)
        smem[(tx * 4 + j) * 65 + ty * 4 + i] = ov[i][j];
    __syncthreads();
    int d  = tid >> 2;
    int s4 = (tid & 3) * 16;
    unsigned short tmp[16];
    #pragma unroll
    for (int t = 0; t < 16; ++t)
      tmp[t] = f2bf(smem[d * 65 + s4 + t]);
    unsigned short* dst = ws + V_OFF +
        ((size_t)(bb * NHd + head) * HDd + d) * Sdim + sbase + s4;
    *(uint4*)&dst[0] = *(uint4*)&tmp[0];
    *(uint4*)&dst[8] = *(uint4*)&tmp[8];
  }
}

// ---------------- MFMA flash attention ----------------
// Block: 4 waves, 64 queries of one (b,h); wave w owns queries w*16..w*16+15.
// K-loop: tiles of 64 keys. QK^T = full (qh+ql)·(kh+kl) via 4 term-pairs of
// K=32 MFMAs (8 per 16x16 subtile) — cross terms included. PV plain bf16.
__global__ __launch_bounds__(256, 2) void attn_mfma(
    const unsigned short* __restrict__ qhl,
    const unsigned short* __restrict__ khl,
    const unsigned short* __restrict__ vt,
    const int* __restrict__ mask,
    float* __restrict__ out)
{
  __shared__ unsigned short Ks[64][136];   // Q staging, then K tiles
  __shared__ unsigned short Vs[64][72];    // V tile, [d][key]
  __shared__ unsigned short Pw[4][16][72]; // per-wave P (C->A layout roundtrip)
  __shared__ float msk[64];

  const int tid  = threadIdx.x;
  const int wave = tid >> 6;
  const int lane = tid & 63;
  const int l16  = lane & 15;
  const int quad = lane >> 4;

  const int qt = blockIdx.x & 15;     // S/64 = 16 q-tiles
  const int bh = blockIdx.x >> 4;
  const int bb = bh >> 4;
  const int q0 = qt * 64;

  // --- stage Q tile, read A-frags into registers ---
  {
    int row = tid >> 2, seg = tid & 3;
    const unsigned short* src = qhl + ((size_t)bh * Sdim + q0 + row) * 128;
    #pragma unroll
    for (int i = 0; i < 4; ++i) {
      int c = seg * 32 + i * 8;
      *(uint4*)&Ks[row][c] = *(const uint4*)&src[c];
    }
  }
  __syncthreads();
  bf16x8 qf[4];   // [0,1]=hi chunks, [2,3]=lo chunks
  {
    int qrow = wave * 16 + l16;
    #pragma unroll
    for (int kk = 0; kk < 4; ++kk)
      qf[kk] = *(const bf16x8*)&Ks[qrow][kk * 32 + quad * 8];
  }

  f32x4 O[4] = {{0.f,0.f,0.f,0.f},{0.f,0.f,0.f,0.f},{0.f,0.f,0.f,0.f},{0.f,0.f,0.f,0.f}};
  float mrow[4] = {-INFINITY, -INFINITY, -INFINITY, -INFINITY};
  float lrow[4] = {0.f, 0.f, 0.f, 0.f};

  #pragma unroll 1
  for (int kt = 0; kt < Sdim / 64; ++kt) {
    __syncthreads();
    // stage K hi/lo tile (64 keys x 128)
    {
      int row = tid >> 2, seg = tid & 3;
      const unsigned short* src = khl + ((size_t)bh * Sdim + kt * 64 + row) * 128;
      #pragma unroll
      for (int i = 0; i < 4; ++i) {
        int c = seg * 32 + i * 8;
        *(uint4*)&Ks[row][c] = *(const uint4*)&src[c];
      }
    }
    // stage V tile [d][key]
    {
      int d = tid >> 2, part = tid & 3;
      const unsigned short* src = vt + ((size_t)bh * HDd + d) * Sdim + kt * 64;
      *(uint4*)&Vs[d][part * 16]     = *(const uint4*)&src[part * 16];
      *(uint4*)&Vs[d][part * 16 + 8] = *(const uint4*)&src[part * 16 + 8];
    }
    if (tid < 64)
      msk[tid] = (mask[bb * Sdim + kt * 64 + tid] != 0) ? 1.f : 0.f;
    __syncthreads();

    // QK^T: 4 key-subtiles; full product = qh·kh + ql·kh + qh·kl + ql·kl
    f32x4 sc[4];
    #pragma unroll
    for (int ns = 0; ns < 4; ++ns) {
      f32x4 c = {0.f, 0.f, 0.f, 0.f};
      int krow = ns * 16 + l16;
      bf16x8 kf[4];
      #pragma unroll
      for (int kk = 0; kk < 4; ++kk)
        kf[kk] = *(const bf16x8*)&Ks[krow][kk * 32 + quad * 8];
      // hi·hi
      c = __builtin_amdgcn_mfma_f32_16x16x32_bf16(qf[0], kf[0], c, 0, 0, 0);
      c = __builtin_amdgcn_mfma_f32_16x16x32_bf16(qf[1], kf[1], c, 0, 0, 0);
      // lo·hi
      c = __builtin_amdgcn_mfma_f32_16x16x32_bf16(qf[2], kf[0], c, 0, 0, 0);
      c = __builtin_amdgcn_mfma_f32_16x16x32_bf16(qf[3], kf[1], c, 0, 0, 0);
      // hi·lo
      c = __builtin_amdgcn_mfma_f32_16x16x32_bf16(qf[0], kf[2], c, 0, 0, 0);
      c = __builtin_amdgcn_mfma_f32_16x16x32_bf16(qf[1], kf[3], c, 0, 0, 0);
      // lo·lo
      c = __builtin_amdgcn_mfma_f32_16x16x32_bf16(qf[2], kf[2], c, 0, 0, 0);
      c = __builtin_amdgcn_mfma_f32_16x16x32_bf16(qf[3], kf[3], c, 0, 0, 0);
      sc[ns] = c;
    }

    // mask + scale, row max
    float rmax[4] = {-INFINITY, -INFINITY, -INFINITY, -INFINITY};
    #pragma unroll
    for (int ns = 0; ns < 4; ++ns) {
      float mk = msk[ns * 16 + l16];
      #pragma unroll
      for (int r = 0; r < 4; ++r) {
        float s = (mk != 0.f) ? -10000.f : sc[ns][r] * 8.f;
        sc[ns][r] = s;
        rmax[r] = fmaxf(rmax[r], s);
      }
    }
    #pragma unroll
    for (int r = 0; r < 4; ++r) {
      float v = rmax[r];
      v = fmaxf(v, __shfl_xor(v, 1, 16));
      v = fmaxf(v, __shfl_xor(v, 2, 16));
      v = fmaxf(v, __shfl_xor(v, 4, 16));
      v = fmaxf(v, __shfl_xor(v, 8, 16));
      rmax[r] = v;
    }

    float alpha[4];
    #pragma unroll
    for (int r = 0; r < 4; ++r) {
      float mn = fmaxf(mrow[r], rmax[r]);
      alpha[r] = __expf(mrow[r] - mn);
      mrow[r] = mn;
      lrow[r] *= alpha[r];
    }
    #pragma unroll
    for (int d = 0; d < 4; ++d)
      #pragma unroll
      for (int r = 0; r < 4; ++r) O[d][r] *= alpha[r];

    // exp, row-sum, write P (bf16) to per-wave LDS
    float rsum[4] = {0.f, 0.f, 0.f, 0.f};
    #pragma unroll
    for (int ns = 0; ns < 4; ++ns) {
      #pragma unroll
      for (int r = 0; r < 4; ++r) {
        float p = __expf(sc[ns][r] - mrow[r]);
        rsum[r] += p;
        Pw[wave][quad * 4 + r][ns * 16 + l16] = f2bf(p);
      }
    }
    #pragma unroll
    for (int r = 0; r < 4; ++r) {
      float v = rsum[r];
      v += __shfl_xor(v, 1, 16);
      v += __shfl_xor(v, 2, 16);
      v += __shfl_xor(v, 4, 16);
      v += __shfl_xor(v, 8, 16);
      lrow[r] += v;
    }

    // P·V (wave-local LDS roundtrip; no block barrier needed)
    bf16x8 pf[2];
    #pragma unroll
    for (int kk = 0; kk < 2; ++kk)
      pf[kk] = *(const bf16x8*)&Pw[wave][l16][kk * 32 + quad * 8];
    #pragma unroll
    for (int d = 0; d < 4; ++d) {
      int vrow = d * 16 + l16;
      #pragma unroll
      for (int kk = 0; kk < 2; ++kk) {
        bf16x8 vf = *(const bf16x8*)&Vs[vrow][kk * 32 + quad * 8];
        O[d] = __builtin_amdgcn_mfma_f32_16x16x32_bf16(pf[kk], vf, O[d], 0, 0, 0);
      }
    }
  }

  // epilogue
  const int h = bh & 15;
  #pragma unroll
  for (int r = 0; r < 4; ++r) {
    float inv = 1.f / lrow[r];
    int q = q0 + wave * 16 + quad * 4 + r;
    float* dst = out + ((size_t)bb * Sdim + q) * Hdim + h * HDd;
    #pragma unroll
    for (int d = 0; d < 4; ++d)
      dst[d * 16 + l16] = O[d][r] * inv;
  }
}

extern "C" void kernel_launch(void* const* d_in, const int* in_sizes, int n_in,
                              void* d_out, int out_size, void* d_ws, size_t ws_size,
                              hipStream_t stream) {
  const float* hs   = (const float*)d_in[0];
  const int*   mask = (const int*)d_in[1];
  const float* w    = (const float*)d_in[2];
  const float* bias = (const float*)d_in[3];
  float* out = (float*)d_out;
  unsigned short* ws = (unsigned short*)d_ws;   // 83.9 MB used

  dim3 gg(N3H / BN, (Bdim * Sdim) / BM);        // (48, 128)
  qkv_gemm<<<gg, 256, 0, stream>>>(hs, w, bias, ws);

  attn_mfma<<<Bdim * NHd * (Sdim / 64), 256, 0, stream>>>(
      ws + Q_OFF, ws + K_OFF, ws + V_OFF, mask, out);
}

// Round 4
// 373.556 us; speedup vs baseline: 4.6610x; 2.3962x over previous
//
#include <hip/hip_runtime.h>
#include <math.h>

#define Bdim 8
#define Sdim 1024
#define Hdim 1024
#define NHd 16
#define HDd 64
#define N3H 3072

// ws layout (ushort elements)
#define Q_OFF   0u
#define K_OFF   16777216u
#define V_OFF   33554432u
#define WH_OFF  41943040u
#define WL_OFF  45088768u
// d_out scratch layout (ushort elements): Ahi, Alo
#define AHI_OFF 0u
#define ALO_OFF 8388608u

typedef __bf16 bf16x8 __attribute__((ext_vector_type(8)));
typedef float  f32x4  __attribute__((ext_vector_type(4)));

__device__ __forceinline__ unsigned short f2bf(float x) {
  unsigned b = __builtin_bit_cast(unsigned, x);
  return (unsigned short)((b + 0x7FFFu + ((b >> 16) & 1u)) >> 16);
}
__device__ __forceinline__ float bf2f(unsigned short h) {
  unsigned b = ((unsigned)h) << 16;
  return __builtin_bit_cast(float, b);
}
__device__ __forceinline__ void split_hl(float v, unsigned short& h, unsigned short& l) {
  h = f2bf(v);
  l = f2bf(v - bf2f(h));
}
__device__ __forceinline__ void async16(void* lds, const void* g) {
  __builtin_amdgcn_global_load_lds((const __attribute__((address_space(1))) unsigned int*)g,
                                   (__attribute__((address_space(3))) unsigned int*)lds, 16, 0, 0);
}

// ---------- convert A (fp32 -> hi/lo bf16 planes, into d_out scratch) ----------
__global__ __launch_bounds__(256) void convert_A(
    const float* __restrict__ A, unsigned short* __restrict__ outp)
{
  size_t i = ((size_t)blockIdx.x * 256 + threadIdx.x) * 8;
  float4 a0 = *(const float4*)&A[i];
  float4 a1 = *(const float4*)&A[i + 4];
  float av[8] = {a0.x, a0.y, a0.z, a0.w, a1.x, a1.y, a1.z, a1.w};
  unsigned short h[8], l[8];
  #pragma unroll
  for (int j = 0; j < 8; ++j) split_hl(av[j], h[j], l[j]);
  *(uint4*)&outp[AHI_OFF + i] = *(uint4*)h;
  *(uint4*)&outp[ALO_OFF + i] = *(uint4*)l;
}

// ---------- convert W (fp32 [K][N] -> W^T hi/lo bf16 [N][K], into ws) ----------
__global__ __launch_bounds__(256) void convert_W(
    const float* __restrict__ W, unsigned short* __restrict__ ws)
{
  __shared__ float T[64][65];
  const int tid = threadIdx.x;
  const int n0 = blockIdx.x * 64;
  const int k0 = blockIdx.y * 64;
  #pragma unroll
  for (int r = 0; r < 4; ++r) {
    int k = r * 16 + (tid >> 4);
    int n = (tid & 15) * 4;
    float4 v = *(const float4*)&W[(size_t)(k0 + k) * N3H + n0 + n];
    T[k][n + 0] = v.x; T[k][n + 1] = v.y; T[k][n + 2] = v.z; T[k][n + 3] = v.w;
  }
  __syncthreads();
  int n = tid >> 2;
  int kl = (tid & 3) * 16;
  unsigned short h[16], l[16];
  #pragma unroll
  for (int i = 0; i < 16; ++i) split_hl(T[kl + i][n], h[i], l[i]);
  size_t base = (size_t)(n0 + n) * 1024 + k0 + kl;
  *(uint4*)&ws[WH_OFF + base]     = *(uint4*)&h[0];
  *(uint4*)&ws[WH_OFF + base + 8] = *(uint4*)&h[8];
  *(uint4*)&ws[WL_OFF + base]     = *(uint4*)&l[0];
  *(uint4*)&ws[WL_OFF + base + 8] = *(uint4*)&l[8];
}

// ---------- MFMA QKV GEMM: C = A(8192x1024) * W(1024x3072) + bias ----------
// 128x128 tile, BK=32, 4 waves in 2x2; 3-term split: ah*wh + al*wh + ah*wl.
__global__ __launch_bounds__(256, 2) void qkv_mfma(
    const unsigned short* __restrict__ ao,   // d_out scratch: Ahi/Alo
    const unsigned short* __restrict__ ws,   // W planes (in), QKV planes (out)
    const float* __restrict__ bias,
    unsigned short* __restrict__ wso)
{
  __shared__ unsigned short sA[2][128 * 32];
  __shared__ unsigned short sB[2][128 * 32];

  const int tid  = threadIdx.x;
  const int wave = tid >> 6;
  const int lane = tid & 63;
  const int l16  = lane & 15;
  const int quad = lane >> 4;

  const int n0 = blockIdx.x * 128;
  const int m0 = blockIdx.y * 128;
  const int wm = (wave >> 1) * 64;
  const int wn = (wave & 1) * 64;

  const unsigned short* Ah = ao + AHI_OFF;
  const unsigned short* Al = ao + ALO_OFF;
  const unsigned short* Wh = ws + WH_OFF;
  const unsigned short* Wl = ws + WL_OFF;

  f32x4 acc[4][4];
  #pragma unroll
  for (int i = 0; i < 4; ++i)
    #pragma unroll
    for (int j = 0; j < 4; ++j) acc[i][j] = (f32x4){0.f, 0.f, 0.f, 0.f};

  for (int kt = 0; kt < 1024; kt += 32) {
    __syncthreads();
    #pragma unroll
    for (int r = 0; r < 2; ++r) {
      int chunk = r * 256 + tid;           // 0..511
      int row = chunk >> 2;
      int c8  = (chunk & 3) << 3;
      int ldsoff = (r * 256 + wave * 64) * 8;
      async16(&sA[0][ldsoff], &Ah[(size_t)(m0 + row) * 1024 + kt + c8]);
      async16(&sA[1][ldsoff], &Al[(size_t)(m0 + row) * 1024 + kt + c8]);
      async16(&sB[0][ldsoff], &Wh[(size_t)(n0 + row) * 1024 + kt + c8]);
      async16(&sB[1][ldsoff], &Wl[(size_t)(n0 + row) * 1024 + kt + c8]);
    }
    __syncthreads();

    bf16x8 af[4][2], bf[4][2];
    #pragma unroll
    for (int i = 0; i < 4; ++i) {
      int row = wm + i * 16 + l16;
      af[i][0] = *(const bf16x8*)&sA[0][row * 32 + quad * 8];
      af[i][1] = *(const bf16x8*)&sA[1][row * 32 + quad * 8];
    }
    #pragma unroll
    for (int j = 0; j < 4; ++j) {
      int row = wn + j * 16 + l16;
      bf[j][0] = *(const bf16x8*)&sB[0][row * 32 + quad * 8];
      bf[j][1] = *(const bf16x8*)&sB[1][row * 32 + quad * 8];
    }
    #pragma unroll
    for (int i = 0; i < 4; ++i)
      #pragma unroll
      for (int j = 0; j < 4; ++j) {
        acc[i][j] = __builtin_amdgcn_mfma_f32_16x16x32_bf16(af[i][0], bf[j][0], acc[i][j], 0, 0, 0);
        acc[i][j] = __builtin_amdgcn_mfma_f32_16x16x32_bf16(af[i][1], bf[j][0], acc[i][j], 0, 0, 0);
        acc[i][j] = __builtin_amdgcn_mfma_f32_16x16x32_bf16(af[i][0], bf[j][1], acc[i][j], 0, 0, 0);
      }
  }

  // ---- epilogue: bias + scatter ----
  const int ncol0 = n0 + wn;               // 64-aligned -> one (which, head)
  const int which = (ncol0 >> 6) % 3;
  const int head  = ncol0 / 192;
  const int mrow0 = m0 + wm;               // 64-aligned, within one b
  const int bb = mrow0 >> 10;
  const int sb = mrow0 & 1023;

  float bs[4];
  #pragma unroll
  for (int j = 0; j < 4; ++j) bs[j] = bias[ncol0 + j * 16 + l16];

  if (which < 2) {
    unsigned short* dst = wso + (which ? K_OFF : Q_OFF) +
        ((size_t)(bb * NHd + head) * Sdim + sb) * 128;
    #pragma unroll
    for (int i = 0; i < 4; ++i)
      #pragma unroll
      for (int j = 0; j < 4; ++j) {
        int d = j * 16 + l16;
        #pragma unroll
        for (int r = 0; r < 4; ++r) {
          int s = i * 16 + quad * 4 + r;
          float v = acc[i][j][r] + bs[j];
          unsigned short h, l;
          split_hl(v, h, l);
          dst[(size_t)s * 128 + d]      = h;
          dst[(size_t)s * 128 + 64 + d] = l;
        }
      }
  } else {
    unsigned short* dst = wso + V_OFF + (size_t)(bb * NHd + head) * HDd * Sdim;
    #pragma unroll
    for (int i = 0; i < 4; ++i)
      #pragma unroll
      for (int j = 0; j < 4; ++j) {
        int d = j * 16 + l16;
        int s0 = sb + i * 16 + quad * 4;
        unsigned short p[4];
        #pragma unroll
        for (int r = 0; r < 4; ++r) p[r] = f2bf(acc[i][j][r] + bs[j]);
        *(uint2*)&dst[(size_t)d * Sdim + s0] = *(uint2*)p;
      }
  }
}

// ---------------- MFMA flash attention (unchanged from round 3) ----------------
__global__ __launch_bounds__(256, 2) void attn_mfma(
    const unsigned short* __restrict__ qhl,
    const unsigned short* __restrict__ khl,
    const unsigned short* __restrict__ vt,
    const int* __restrict__ mask,
    float* __restrict__ out)
{
  __shared__ unsigned short Ks[64][136];
  __shared__ unsigned short Vs[64][72];
  __shared__ unsigned short Pw[4][16][72];
  __shared__ float msk[64];

  const int tid  = threadIdx.x;
  const int wave = tid >> 6;
  const int lane = tid & 63;
  const int l16  = lane & 15;
  const int quad = lane >> 4;

  const int qt = blockIdx.x & 15;
  const int bh = blockIdx.x >> 4;
  const int bb = bh >> 4;
  const int q0 = qt * 64;

  {
    int row = tid >> 2, seg = tid & 3;
    const unsigned short* src = qhl + ((size_t)bh * Sdim + q0 + row) * 128;
    #pragma unroll
    for (int i = 0; i < 4; ++i) {
      int c = seg * 32 + i * 8;
      *(uint4*)&Ks[row][c] = *(const uint4*)&src[c];
    }
  }
  __syncthreads();
  bf16x8 qf[4];
  {
    int qrow = wave * 16 + l16;
    #pragma unroll
    for (int kk = 0; kk < 4; ++kk)
      qf[kk] = *(const bf16x8*)&Ks[qrow][kk * 32 + quad * 8];
  }

  f32x4 O[4] = {{0.f,0.f,0.f,0.f},{0.f,0.f,0.f,0.f},{0.f,0.f,0.f,0.f},{0.f,0.f,0.f,0.f}};
  float mrow[4] = {-INFINITY, -INFINITY, -INFINITY, -INFINITY};
  float lrow[4] = {0.f, 0.f, 0.f, 0.f};

  #pragma unroll 1
  for (int kt = 0; kt < Sdim / 64; ++kt) {
    __syncthreads();
    {
      int row = tid >> 2, seg = tid & 3;
      const unsigned short* src = khl + ((size_t)bh * Sdim + kt * 64 + row) * 128;
      #pragma unroll
      for (int i = 0; i < 4; ++i) {
        int c = seg * 32 + i * 8;
        *(uint4*)&Ks[row][c] = *(const uint4*)&src[c];
      }
    }
    {
      int d = tid >> 2, part = tid & 3;
      const unsigned short* src = vt + ((size_t)bh * HDd + d) * Sdim + kt * 64;
      *(uint4*)&Vs[d][part * 16]     = *(const uint4*)&src[part * 16];
      *(uint4*)&Vs[d][part * 16 + 8] = *(const uint4*)&src[part * 16 + 8];
    }
    if (tid < 64)
      msk[tid] = (mask[bb * Sdim + kt * 64 + tid] != 0) ? 1.f : 0.f;
    __syncthreads();

    f32x4 sc[4];
    #pragma unroll
    for (int ns = 0; ns < 4; ++ns) {
      f32x4 c = {0.f, 0.f, 0.f, 0.f};
      int krow = ns * 16 + l16;
      bf16x8 kf[4];
      #pragma unroll
      for (int kk = 0; kk < 4; ++kk)
        kf[kk] = *(const bf16x8*)&Ks[krow][kk * 32 + quad * 8];
      c = __builtin_amdgcn_mfma_f32_16x16x32_bf16(qf[0], kf[0], c, 0, 0, 0);
      c = __builtin_amdgcn_mfma_f32_16x16x32_bf16(qf[1], kf[1], c, 0, 0, 0);
      c = __builtin_amdgcn_mfma_f32_16x16x32_bf16(qf[2], kf[0], c, 0, 0, 0);
      c = __builtin_amdgcn_mfma_f32_16x16x32_bf16(qf[3], kf[1], c, 0, 0, 0);
      c = __builtin_amdgcn_mfma_f32_16x16x32_bf16(qf[0], kf[2], c, 0, 0, 0);
      c = __builtin_amdgcn_mfma_f32_16x16x32_bf16(qf[1], kf[3], c, 0, 0, 0);
      c = __builtin_amdgcn_mfma_f32_16x16x32_bf16(qf[2], kf[2], c, 0, 0, 0);
      c = __builtin_amdgcn_mfma_f32_16x16x32_bf16(qf[3], kf[3], c, 0, 0, 0);
      sc[ns] = c;
    }

    float rmax[4] = {-INFINITY, -INFINITY, -INFINITY, -INFINITY};
    #pragma unroll
    for (int ns = 0; ns < 4; ++ns) {
      float mk = msk[ns * 16 + l16];
      #pragma unroll
      for (int r = 0; r < 4; ++r) {
        float s = (mk != 0.f) ? -10000.f : sc[ns][r] * 8.f;
        sc[ns][r] = s;
        rmax[r] = fmaxf(rmax[r], s);
      }
    }
    #pragma unroll
    for (int r = 0; r < 4; ++r) {
      float v = rmax[r];
      v = fmaxf(v, __shfl_xor(v, 1, 16));
      v = fmaxf(v, __shfl_xor(v, 2, 16));
      v = fmaxf(v, __shfl_xor(v, 4, 16));
      v = fmaxf(v, __shfl_xor(v, 8, 16));
      rmax[r] = v;
    }

    float alpha[4];
    #pragma unroll
    for (int r = 0; r < 4; ++r) {
      float mn = fmaxf(mrow[r], rmax[r]);
      alpha[r] = __expf(mrow[r] - mn);
      mrow[r] = mn;
      lrow[r] *= alpha[r];
    }
    #pragma unroll
    for (int d = 0; d < 4; ++d)
      #pragma unroll
      for (int r = 0; r < 4; ++r) O[d][r] *= alpha[r];

    float rsum[4] = {0.f, 0.f, 0.f, 0.f};
    #pragma unroll
    for (int ns = 0; ns < 4; ++ns) {
      #pragma unroll
      for (int r = 0; r < 4; ++r) {
        float p = __expf(sc[ns][r] - mrow[r]);
        rsum[r] += p;
        Pw[wave][quad * 4 + r][ns * 16 + l16] = f2bf(p);
      }
    }
    #pragma unroll
    for (int r = 0; r < 4; ++r) {
      float v = rsum[r];
      v += __shfl_xor(v, 1, 16);
      v += __shfl_xor(v, 2, 16);
      v += __shfl_xor(v, 4, 16);
      v += __shfl_xor(v, 8, 16);
      lrow[r] += v;
    }

    bf16x8 pf[2];
    #pragma unroll
    for (int kk = 0; kk < 2; ++kk)
      pf[kk] = *(const bf16x8*)&Pw[wave][l16][kk * 32 + quad * 8];
    #pragma unroll
    for (int d = 0; d < 4; ++d) {
      int vrow = d * 16 + l16;
      #pragma unroll
      for (int kk = 0; kk < 2; ++kk) {
        bf16x8 vf = *(const bf16x8*)&Vs[vrow][kk * 32 + quad * 8];
        O[d] = __builtin_amdgcn_mfma_f32_16x16x32_bf16(pf[kk], vf, O[d], 0, 0, 0);
      }
    }
  }

  const int h = bh & 15;
  #pragma unroll
  for (int r = 0; r < 4; ++r) {
    float inv = 1.f / lrow[r];
    int q = q0 + wave * 16 + quad * 4 + r;
    float* dst = out + ((size_t)bb * Sdim + q) * Hdim + h * HDd;
    #pragma unroll
    for (int d = 0; d < 4; ++d)
      dst[d * 16 + l16] = O[d][r] * inv;
  }
}

extern "C" void kernel_launch(void* const* d_in, const int* in_sizes, int n_in,
                              void* d_out, int out_size, void* d_ws, size_t ws_size,
                              hipStream_t stream) {
  const float* hs   = (const float*)d_in[0];
  const int*   mask = (const int*)d_in[1];
  const float* w    = (const float*)d_in[2];
  const float* bias = (const float*)d_in[3];
  float* out = (float*)d_out;
  unsigned short* ws = (unsigned short*)d_ws;        // uses 96,468,992 B
  unsigned short* ao = (unsigned short*)d_out;       // A hi/lo scratch (overwritten by attn)

  convert_A<<<4096, 256, 0, stream>>>(hs, ao);
  convert_W<<<dim3(N3H / 64, 1024 / 64), 256, 0, stream>>>(w, ws);

  qkv_mfma<<<dim3(N3H / 128, 8192 / 128), 256, 0, stream>>>(ao, ws, bias, ws);

  attn_mfma<<<Bdim * NHd * (Sdim / 64), 256, 0, stream>>>(
      ws + Q_OFF, ws + K_OFF, ws + V_OFF, mask, out);
}